// Round 9
// baseline (138.461 us; speedup 1.0000x reference)
//
#include <hip/hip_runtime.h>

#define NA    69      // 3 * (4*6 - 1) angles
#define KDIM  512
#define BM    64      // fused: rows per block
#define BK    64      // gemm K chunk
#define GT    256     // fused block threads (4 waves)
#define ASTR  68      // angle LDS row stride (floats)
#define CROWS 256
#define BLK   256
#define LSTRIDE 33

typedef __attribute__((ext_vector_type(8))) short short8v;   // 8 bf16 = 16B
typedef __attribute__((ext_vector_type(4))) float f32x4;
typedef __attribute__((ext_vector_type(4))) unsigned short us4;

__device__ __forceinline__ unsigned short bf16_rne(float x) {
    unsigned u = __float_as_uint(x);
    unsigned r = u + 0x7FFF + ((u >> 16) & 1);
    return (unsigned short)(r >> 16);
}

// ==== init: W (69x512 f32) -> bf16 hi/lo in MFMA-fragment order =============
// tid = ksg*320 + nt*64 + lane ; holds B[n=nt*16+(l&15)][k=ksg*32+(l>>4)*8+j]
__global__ void w_convert(const float* __restrict__ W,
                          unsigned short* __restrict__ Whf,
                          unsigned short* __restrict__ Wlf)
{
    int tid = blockIdx.x * 256 + threadIdx.x;
    if (tid >= 16 * 5 * 64) return;
    int ksg = tid / 320;
    int rem = tid % 320;
    int nt  = rem / 64;
    int l   = rem % 64;
    int n   = nt * 16 + (l & 15);
    int k   = ksg * 32 + (l >> 4) * 8;
#pragma unroll
    for (int j = 0; j < 8; ++j) {
        float w = (n < NA) ? W[(size_t)n * KDIM + k + j] : 0.f;
        unsigned short h = bf16_rne(w);
        float hf = __uint_as_float((unsigned)h << 16);
        Whf[(size_t)tid * 8 + j] = h;
        Wlf[(size_t)tid * 8 + j] = bf16_rne(w - hf);
    }
}

// ==== PROVEN 2-lane/row circuit helpers (R5/R6, verbatim) ===================
// par = owns qubit-0 bit; lane holds 32 amps (wires 1..5 = masks 16,8,4,2,1)

template<int M0, int M1>
__device__ __forceinline__ void rxx_l32(float* sr, float* si, float th) {
    float h = 0.5f * th, c, sn;
    __sincosf(h, &sn, &c);
    constexpr int M = M0 | M1;
#pragma unroll
    for (int j = 0; j < 32; ++j) {
        if (j & M0) continue;
        const int p = j ^ M;
        float ar = sr[j], ai = si[j], br = sr[p], bi = si[p];
        sr[j] = c * ar + sn * bi;
        si[j] = c * ai - sn * br;
        sr[p] = c * br + sn * ai;
        si[p] = c * bi - sn * ar;
    }
}

template<int M>
__device__ __forceinline__ void u3_l32(float* sr, float* si,
                                       float th, float ph, float la) {
    float h = 0.5f * th;
    float ct, st, cph, sph, cla, sla;
    __sincosf(h,  &st,  &ct);
    __sincosf(ph, &sph, &cph);
    __sincosf(la, &sla, &cla);
    float cpl = cph * cla - sph * sla;
    float spl = sph * cla + cph * sla;
    float m01r = -cla * st, m01i = -sla * st;
    float m10r =  cph * st, m10i =  sph * st;
    float m11r =  cpl * ct, m11i =  spl * ct;
#pragma unroll
    for (int j = 0; j < 32; ++j) {
        if (j & M) continue;
        const int p = j | M;
        float ar = sr[j], ai = si[j], br = sr[p], bi = si[p];
        sr[j] = ct * ar + m01r * br - m01i * bi;
        si[j] = ct * ai + m01r * bi + m01i * br;
        sr[p] = m10r * ar - m10i * ai + m11r * br - m11i * bi;
        si[p] = m10r * ai + m10i * ar + m11r * bi + m11i * br;
    }
}

__device__ __forceinline__ void rxx01_x32(float* sr, float* si, float th) {
    float h = 0.5f * th, c, sn;
    __sincosf(h, &sn, &c);
#pragma unroll
    for (int j = 0; j < 16; ++j) {
        const int p = j + 16;
        float crj = __shfl_xor(sr[p], 32), cij = __shfl_xor(si[p], 32);
        float crp = __shfl_xor(sr[j], 32), cip = __shfl_xor(si[j], 32);
        float aj = sr[j], bj = si[j], ap = sr[p], bp = si[p];
        sr[j] = c * aj + sn * cij;  si[j] = c * bj - sn * crj;
        sr[p] = c * ap + sn * cip;  si[p] = c * bp - sn * crp;
    }
}

__device__ __forceinline__ void u30_x32(float* sr, float* si, int par,
                                        float th, float ph, float la) {
    float h = 0.5f * th;
    float ct, st, cph, sph, cla, sla;
    __sincosf(h,  &st,  &ct);
    __sincosf(ph, &sph, &cph);
    __sincosf(la, &sla, &cla);
    float cpl = cph * cla - sph * sla;
    float spl = sph * cla + cph * sla;
    float m01r = -cla * st, m01i = -sla * st;
    float m10r =  cph * st, m10i =  sph * st;
    float m11r =  cpl * ct, m11i =  spl * ct;
    float Ar = par ? m11r : ct,   Ai = par ? m11i : 0.f;
    float Br = par ? m10r : m01r, Bi = par ? m10i : m01i;
#pragma unroll
    for (int j = 0; j < 32; ++j) {
        float cr = __shfl_xor(sr[j], 32), ci = __shfl_xor(si[j], 32);
        float a = sr[j], bb = si[j];
        sr[j] = Ar * a  - Ai * bb + Br * cr - Bi * ci;
        si[j] = Ar * bb + Ai * a  + Br * ci + Bi * cr;
    }
}

// ==== fused: GEMM (MFMA, prefetched, BM=64) -> LDS angles -> 2-lane circuit =
// grid 1024, 4 waves, LDS 36 KB -> 4 blocks/CU resident (phase-staggered).
// Circuit: waves 0-1 (64 rows x 2 lanes); waves 2-3 exit after the barrier.

__global__ __launch_bounds__(GT, 4) void qrnn_fused5(
    const float* __restrict__ x,
    const unsigned short* __restrict__ Whf, const unsigned short* __restrict__ Wlf,
    const float* __restrict__ b, float* __restrict__ out)
{
    // union LDS: GEMM Ah(8K)|Al(8K)|Bh(10K)|Bl(10K) = 36 KB;
    // circuit reuses as as_[NA][ASTR] = 18.8 KB.
    __shared__ __align__(16) char smem[36864];
    unsigned short* Ah = (unsigned short*)smem;               // 8 KB
    unsigned short* Al = (unsigned short*)(smem + 8192);      // 8 KB
    unsigned short* Bh = (unsigned short*)(smem + 16384);     // 10 KB
    unsigned short* Bl = (unsigned short*)(smem + 26624);     // 10 KB
    float* as_ = (float*)smem;

    const int t    = threadIdx.x;
    const int lane = t & 63;
    const int wave = t >> 6;
    const int mb   = blockIdx.x * BM;

    f32x4 acc[5];
#pragma unroll
    for (int nt = 0; nt < 5; ++nt) acc[nt] = (f32x4){0.f, 0.f, 0.f, 0.f};

    float4 vA[4];
    short8v vBh0, vBl0, vBh1, vBl1, vBh2, vBl2;

    // prefetch chunk 0 (A: 4 float4/thread; B: 640 frags/buffer)
#pragma unroll
    for (int q = 0; q < 4; ++q) {
        int f = t + q * GT, row = f >> 4, col4 = f & 15;
        vA[q] = *reinterpret_cast<const float4*>(
            &x[(size_t)(mb + row) * KDIM + col4 * 4]);
    }
    vBh0 = *reinterpret_cast<const short8v*>(Whf + t * 8);
    vBl0 = *reinterpret_cast<const short8v*>(Wlf + t * 8);
    vBh1 = *reinterpret_cast<const short8v*>(Whf + (t + 256) * 8);
    vBl1 = *reinterpret_cast<const short8v*>(Wlf + (t + 256) * 8);
    if (t < 128) {
        vBh2 = *reinterpret_cast<const short8v*>(Whf + (t + 512) * 8);
        vBl2 = *reinterpret_cast<const short8v*>(Wlf + (t + 512) * 8);
    }

#pragma unroll
    for (int c = 0; c < KDIM / BK; ++c) {
        // ---- write staged chunk c to LDS (A: hi=trunc, lo=rne(residual))
#pragma unroll
        for (int q = 0; q < 4; ++q) {
            int f = t + q * GT, row = f >> 4, col4 = f & 15;
            float vals[4] = {vA[q].x, vA[q].y, vA[q].z, vA[q].w};
            us4 h, lo;
#pragma unroll
            for (int j = 0; j < 4; ++j) {
                unsigned u = __float_as_uint(vals[j]);
                h[j] = (unsigned short)(u >> 16);
                float hf = __uint_as_float(u & 0xFFFF0000u);
                lo[j] = bf16_rne(vals[j] - hf);
            }
            int sw   = (col4 >> 1) ^ (row & 7);
            int byte = row * (BK * 2) + sw * 16 + (col4 & 1) * 8;
            *reinterpret_cast<us4*>((char*)Ah + byte) = h;
            *reinterpret_cast<us4*>((char*)Al + byte) = lo;
        }
        *reinterpret_cast<short8v*>(Bh + t * 8) = vBh0;
        *reinterpret_cast<short8v*>(Bl + t * 8) = vBl0;
        *reinterpret_cast<short8v*>(Bh + (t + 256) * 8) = vBh1;
        *reinterpret_cast<short8v*>(Bl + (t + 256) * 8) = vBl1;
        if (t < 128) {
            *reinterpret_cast<short8v*>(Bh + (t + 512) * 8) = vBh2;
            *reinterpret_cast<short8v*>(Bl + (t + 512) * 8) = vBl2;
        }
        // ---- issue chunk c+1 loads (in flight across compute phase)
        if (c + 1 < KDIM / BK) {
#pragma unroll
            for (int q = 0; q < 4; ++q) {
                int f = t + q * GT, row = f >> 4, col4 = f & 15;
                vA[q] = *reinterpret_cast<const float4*>(
                    &x[(size_t)(mb + row) * KDIM + (c + 1) * BK + col4 * 4]);
            }
            size_t base = (size_t)(c + 1) * 5120;
            vBh0 = *reinterpret_cast<const short8v*>(Whf + base + t * 8);
            vBl0 = *reinterpret_cast<const short8v*>(Wlf + base + t * 8);
            vBh1 = *reinterpret_cast<const short8v*>(Whf + base + (t + 256) * 8);
            vBl1 = *reinterpret_cast<const short8v*>(Wlf + base + (t + 256) * 8);
            if (t < 128) {
                vBh2 = *reinterpret_cast<const short8v*>(Whf + base + (t + 512) * 8);
                vBl2 = *reinterpret_cast<const short8v*>(Wlf + base + (t + 512) * 8);
            }
        }
        __syncthreads();

        // ---- compute chunk c: 2 K-steps x 1 m-tile x 5 n-tiles x 3 products
#pragma unroll
        for (int ks = 0; ks < BK / 32; ++ks) {
            int row = wave * 16 + (lane & 15);
            int c8  = ks * 4 + (lane >> 4);
            int sw  = c8 ^ (row & 7);
            int abyte = row * (BK * 2) + sw * 16;
            short8v ah = *reinterpret_cast<const short8v*>((char*)Ah + abyte);
            short8v al = *reinterpret_cast<const short8v*>((char*)Al + abyte);
#pragma unroll
            for (int nt = 0; nt < 5; ++nt) {
                int boff = ((ks * 5 + nt) * 64 + lane) * 8;
                short8v bh = *reinterpret_cast<const short8v*>(Bh + boff);
                short8v bl = *reinterpret_cast<const short8v*>(Bl + boff);
                acc[nt] = __builtin_amdgcn_mfma_f32_16x16x32_bf16(ah, bh, acc[nt], 0, 0, 0);
                acc[nt] = __builtin_amdgcn_mfma_f32_16x16x32_bf16(al, bh, acc[nt], 0, 0, 0);
                acc[nt] = __builtin_amdgcn_mfma_f32_16x16x32_bf16(ah, bl, acc[nt], 0, 0, 0);
            }
        }
        __syncthreads();
    }

    // ---- epilogue: angles into LDS (GEMM buffers dead after last barrier)
#pragma unroll
    for (int nt = 0; nt < 5; ++nt) {
        int n = nt * 16 + (lane & 15);
        if (n < NA) {
            float bias = b[n];
            int m0 = wave * 16 + (lane >> 4) * 4;
            f32x4 v = acc[nt];
            float4 o = make_float4(v[0] + bias, v[1] + bias,
                                   v[2] + bias, v[3] + bias);
            *reinterpret_cast<float4*>(&as_[n * ASTR + m0]) = o;
        }
    }
    __syncthreads();

    // ---- circuit phase: PROVEN 2-lane/row on waves 0-1 (64 rows)
    if (wave < 2) {
        const int par = lane >> 5;
        const int rl  = (lane & 31) + wave * 32;    // local row 0..63

        float sr[32], si[32];
#pragma unroll
        for (int j = 0; j < 32; ++j) { sr[j] = 0.f; si[j] = 0.f; }
        if (par == 0) sr[0] = 1.f;

#define ANG(i) as_[(i) * ASTR + rl]
#pragma unroll 1
        for (int lay = 0; lay < 3; ++lay) {
            const int base = lay * 23;
            rxx01_x32(sr, si, ANG(base + 0));
            u30_x32  (sr, si, par, ANG(base + 1), ANG(base + 2), ANG(base + 3));
            rxx_l32<16, 8>(sr, si, ANG(base + 4));
            u3_l32<16>(sr, si, ANG(base + 5),  ANG(base + 6),  ANG(base + 7));
            rxx_l32<8, 4>(sr, si, ANG(base + 8));
            u3_l32<8>(sr, si, ANG(base + 9),  ANG(base + 10), ANG(base + 11));
            rxx_l32<4, 2>(sr, si, ANG(base + 12));
            u3_l32<4>(sr, si, ANG(base + 13), ANG(base + 14), ANG(base + 15));
            rxx_l32<2, 1>(sr, si, ANG(base + 16));
            u3_l32<2>(sr, si, ANG(base + 17), ANG(base + 18), ANG(base + 19));
            u3_l32<1>(sr, si, ANG(base + 20), ANG(base + 21), ANG(base + 22));
        }
#undef ANG

        float* o = out + (size_t)(mb + rl) * 128 + par * 32;
#pragma unroll
        for (int s = 0; s < 8; ++s)
            *reinterpret_cast<float4*>(&o[s * 4]) =
                make_float4(sr[s*4], sr[s*4+1], sr[s*4+2], sr[s*4+3]);
#pragma unroll
        for (int s = 0; s < 8; ++s)
            *reinterpret_cast<float4*>(&o[64 + s * 4]) =
                make_float4(si[s*4], si[s*4+1], si[s*4+2], si[s*4+3]);
    }
}

// ==== fallback (ws too small): fp32 VALU GEMM + global-ang circuit (proven) ==

__global__ __launch_bounds__(BLK, 1) void angles_gemm(
    const float* __restrict__ x, const float* __restrict__ W,
    const float* __restrict__ b, float* __restrict__ ang,
    int row_base, int pass_rows)
{
    const int t     = threadIdx.x;
    const int lrow0 = blockIdx.x * BLK;
    __shared__ float xs[BLK * LSTRIDE];
    float acc[NA];
#pragma unroll
    for (int a = 0; a < NA; ++a) acc[a] = b[a];
    for (int kc = 0; kc < KDIM; kc += 32) {
        __syncthreads();
#pragma unroll
        for (int it = 0; it < 8; ++it) {
            int f4 = it * BLK + t;
            int r  = f4 >> 3;
            int kq = f4 & 7;
            float4 v = *reinterpret_cast<const float4*>(
                &x[(size_t)(row_base + lrow0 + r) * KDIM + kc + kq * 4]);
            *reinterpret_cast<float4*>(&xs[r * LSTRIDE + kq * 4]) = v;
        }
        __syncthreads();
        float4 xv[8];
#pragma unroll
        for (int q = 0; q < 8; ++q)
            xv[q] = *reinterpret_cast<const float4*>(&xs[t * LSTRIDE + q * 4]);
#pragma unroll
        for (int a = 0; a < NA; ++a) {
            const float* wa = W + a * KDIM + kc;
            float s = 0.f;
#pragma unroll
            for (int q = 0; q < 8; ++q) {
                s += xv[q].x * wa[q * 4 + 0];
                s += xv[q].y * wa[q * 4 + 1];
                s += xv[q].z * wa[q * 4 + 2];
                s += xv[q].w * wa[q * 4 + 3];
            }
            acc[a] += s;
        }
    }
    const int lrow = lrow0 + t;
#pragma unroll
    for (int a = 0; a < NA; ++a)
        ang[(size_t)a * pass_rows + lrow] = acc[a];
}

__global__ __launch_bounds__(512, 2) void circuit2g(
    const float* __restrict__ ang, float* __restrict__ out,
    int stride, int row_base)
{
    const int t    = threadIdx.x;
    const int lane = t & 63;
    const int wv   = t >> 6;
    const int par  = lane >> 5;
    const int rl   = (lane & 31) + wv * 32;
    const int row0 = blockIdx.x * CROWS;

    __shared__ float as_[NA][CROWS];
    for (int i = t; i < NA * CROWS; i += 512) {
        int a = i >> 8, r = i & 255;
        as_[a][r] = ang[(size_t)a * stride + row0 + r];
    }
    __syncthreads();

    float sr[32], si[32];
#pragma unroll
    for (int j = 0; j < 32; ++j) { sr[j] = 0.f; si[j] = 0.f; }
    if (par == 0) sr[0] = 1.f;

#define ANG(i) as_[(i)][rl]
#pragma unroll 1
    for (int lay = 0; lay < 3; ++lay) {
        const int base = lay * 23;
        rxx01_x32(sr, si, ANG(base + 0));
        u30_x32  (sr, si, par, ANG(base + 1), ANG(base + 2), ANG(base + 3));
        rxx_l32<16, 8>(sr, si, ANG(base + 4));
        u3_l32<16>(sr, si, ANG(base + 5),  ANG(base + 6),  ANG(base + 7));
        rxx_l32<8, 4>(sr, si, ANG(base + 8));
        u3_l32<8>(sr, si, ANG(base + 9),  ANG(base + 10), ANG(base + 11));
        rxx_l32<4, 2>(sr, si, ANG(base + 12));
        u3_l32<4>(sr, si, ANG(base + 13), ANG(base + 14), ANG(base + 15));
        rxx_l32<2, 1>(sr, si, ANG(base + 16));
        u3_l32<2>(sr, si, ANG(base + 17), ANG(base + 18), ANG(base + 19));
        u3_l32<1>(sr, si, ANG(base + 20), ANG(base + 21), ANG(base + 22));
    }
#undef ANG

    float* o = out + (size_t)(row_base + row0 + rl) * 128 + par * 32;
#pragma unroll
    for (int s = 0; s < 8; ++s)
        *reinterpret_cast<float4*>(&o[s * 4]) =
            make_float4(sr[s*4], sr[s*4+1], sr[s*4+2], sr[s*4+3]);
#pragma unroll
    for (int s = 0; s < 8; ++s)
        *reinterpret_cast<float4*>(&o[64 + s * 4]) =
            make_float4(si[s*4], si[s*4+1], si[s*4+2], si[s*4+3]);
}

// ============================================================================

extern "C" void kernel_launch(void* const* d_in, const int* in_sizes, int n_in,
                              void* d_out, int out_size, void* d_ws, size_t ws_size,
                              hipStream_t stream) {
    const float* x = (const float*)d_in[0];
    const float* W = (const float*)d_in[1];
    const float* b = (const float*)d_in[2];
    float* out = (float*)d_out;
    const int batch = in_sizes[0] / KDIM;          // 65536

    const size_t wf_elems = (size_t)16 * 5 * 64 * 8;   // 40960 per buffer
    const size_t need     = 2 * wf_elems * 2;          // 160 KB

    if (ws_size >= need && (batch % BM) == 0) {
        unsigned short* Whf = (unsigned short*)d_ws;
        unsigned short* Wlf = Whf + wf_elems;
        hipLaunchKernelGGL(w_convert, dim3((16 * 5 * 64 + 255) / 256), dim3(256),
                           0, stream, W, Whf, Wlf);
        hipLaunchKernelGGL(qrnn_fused5, dim3(batch / BM), dim3(GT), 0, stream,
                           x, Whf, Wlf, b, out);
        return;
    }

    // fallback: fp32 VALU GEMM + circuit via global angles, multi-pass
    float* ws = (float*)d_ws;
    size_t max_rows = ws_size / ((size_t)NA * sizeof(float));
    int rows_per_pass = (int)((max_rows / CROWS) * CROWS);
    if (rows_per_pass > batch) rows_per_pass = batch;
    if (rows_per_pass < CROWS) return;   // cannot run
    for (int r0 = 0; r0 < batch; r0 += rows_per_pass) {
        int pr = batch - r0;
        if (pr > rows_per_pass) pr = rows_per_pass;
        hipLaunchKernelGGL(angles_gemm, dim3(pr / BLK), dim3(BLK), 0, stream,
                           x, W, b, ws, r0, pr);
        hipLaunchKernelGGL(circuit2g, dim3(pr / CROWS), dim3(512), 0, stream,
                           ws, out, pr, r0);
    }
}

// Round 13
// 60.054 us; speedup vs baseline: 2.3056x; 2.3056x over previous
//
#include <hip/hip_runtime.h>

#define NA    69      // 3 * (4*6 - 1) angles
#define KDIM  512
#define BM    256     // fused: rows per block
#define BK    64      // gemm K chunk
#define GT    512     // fused block threads (8 waves)
#define CROWS 256
#define BLK   256
#define LSTRIDE 33
#define ASTRIDE 260   // angle LDS row stride (floats): 260%32=4 -> 2-way max

typedef __attribute__((ext_vector_type(8))) short short8v;   // 8 bf16 = 16B
typedef __attribute__((ext_vector_type(4))) float f32x4;
typedef __attribute__((ext_vector_type(4))) unsigned short us4;

__device__ __forceinline__ unsigned short bf16_rne(float x) {
    unsigned u = __float_as_uint(x);
    unsigned r = u + 0x7FFF + ((u >> 16) & 1);
    return (unsigned short)(r >> 16);
}

// ==== init: W (69x512 f32) -> bf16 hi/lo in MFMA-fragment order =============
// tid = ksg*320 + nt*64 + lane ; holds B[n=nt*16+(l&15)][k=ksg*32+(l>>4)*8+j]
__global__ void w_convert(const float* __restrict__ W,
                          unsigned short* __restrict__ Whf,
                          unsigned short* __restrict__ Wlf)
{
    int tid = blockIdx.x * 256 + threadIdx.x;
    if (tid >= 16 * 5 * 64) return;
    int ksg = tid / 320;
    int rem = tid % 320;
    int nt  = rem / 64;
    int l   = rem % 64;
    int n   = nt * 16 + (l & 15);
    int k   = ksg * 32 + (l >> 4) * 8;
#pragma unroll
    for (int j = 0; j < 8; ++j) {
        float w = (n < NA) ? W[(size_t)n * KDIM + k + j] : 0.f;
        unsigned short h = bf16_rne(w);
        float hf = __uint_as_float((unsigned)h << 16);
        Whf[(size_t)tid * 8 + j] = h;
        Wlf[(size_t)tid * 8 + j] = bf16_rne(w - hf);
    }
}

// ==== circuit gate helpers (2 lanes/row; par = lane>>5) =====================

template<int M0, int M1>
__device__ __forceinline__ void rxx_l(float* sr, float* si, float th) {
    float h = 0.5f * th, c, sn;
    __sincosf(h, &sn, &c);
    constexpr int M = M0 | M1;
#pragma unroll
    for (int j = 0; j < 32; ++j) {
        if (j & M0) continue;
        const int p = j ^ M;
        float ar = sr[j], ai = si[j], br = sr[p], bi = si[p];
        sr[j] = c * ar + sn * bi;
        si[j] = c * ai - sn * br;
        sr[p] = c * br + sn * ai;
        si[p] = c * bi - sn * ar;
    }
}

template<int M>
__device__ __forceinline__ void u3_l(float* sr, float* si,
                                     float th, float ph, float la) {
    float h = 0.5f * th;
    float ct, st, cph, sph, cla, sla;
    __sincosf(h,  &st,  &ct);
    __sincosf(ph, &sph, &cph);
    __sincosf(la, &sla, &cla);
    float cpl = cph * cla - sph * sla;
    float spl = sph * cla + cph * sla;
    float m01r = -cla * st, m01i = -sla * st;
    float m10r =  cph * st, m10i =  sph * st;
    float m11r =  cpl * ct, m11i =  spl * ct;
#pragma unroll
    for (int j = 0; j < 32; ++j) {
        if (j & M) continue;
        const int p = j | M;
        float ar = sr[j], ai = si[j], br = sr[p], bi = si[p];
        sr[j] = ct * ar + m01r * br - m01i * bi;
        si[j] = ct * ai + m01r * bi + m01i * br;
        sr[p] = m10r * ar - m10i * ai + m11r * br - m11i * bi;
        si[p] = m10r * ai + m10i * ar + m11r * bi + m11i * br;
    }
}

__device__ __forceinline__ void rxx01_x(float* sr, float* si, float th) {
    float h = 0.5f * th, c, sn;
    __sincosf(h, &sn, &c);
#pragma unroll
    for (int j = 0; j < 16; ++j) {
        const int p = j + 16;
        float crj = __shfl_xor(sr[p], 32), cij = __shfl_xor(si[p], 32);
        float crp = __shfl_xor(sr[j], 32), cip = __shfl_xor(si[j], 32);
        float aj = sr[j], bj = si[j], ap = sr[p], bp = si[p];
        sr[j] = c * aj + sn * cij;  si[j] = c * bj - sn * crj;
        sr[p] = c * ap + sn * cip;  si[p] = c * bp - sn * crp;
    }
}

__device__ __forceinline__ void u30_x(float* sr, float* si, int par,
                                      float th, float ph, float la) {
    float h = 0.5f * th;
    float ct, st, cph, sph, cla, sla;
    __sincosf(h,  &st,  &ct);
    __sincosf(ph, &sph, &cph);
    __sincosf(la, &sla, &cla);
    float cpl = cph * cla - sph * sla;
    float spl = sph * cla + cph * sla;
    float m01r = -cla * st, m01i = -sla * st;
    float m10r =  cph * st, m10i =  sph * st;
    float m11r =  cpl * ct, m11i =  spl * ct;
    float Ar = par ? m11r : ct,   Ai = par ? m11i : 0.f;
    float Br = par ? m10r : m01r, Bi = par ? m10i : m01i;
#pragma unroll
    for (int j = 0; j < 32; ++j) {
        float cr = __shfl_xor(sr[j], 32), ci = __shfl_xor(si[j], 32);
        float a = sr[j], bb = si[j];
        sr[j] = Ar * a  - Ai * bb + Br * cr - Bi * ci;
        si[j] = Ar * bb + Ai * a  + Br * ci + Bi * cr;
    }
}

// ==== fused: GEMM (MFMA, prefetched) -> LDS angles -> circuit ===============

__global__ __launch_bounds__(GT, 2) void qrnn_fused2(
    const float* __restrict__ x,
    const unsigned short* __restrict__ Whf, const unsigned short* __restrict__ Wlf,
    const float* __restrict__ b, float* __restrict__ out)
{
    // union LDS: GEMM phase uses Ah|Al|Bh|Bl (84 KB); circuit phase reuses it
    // as angle store as_[NA][ASTRIDE] (70.1 KB).
    __shared__ __align__(16) char smem[86016];
    unsigned short* Ah = (unsigned short*)smem;              // 32 KB
    unsigned short* Al = (unsigned short*)(smem + 32768);    // 32 KB
    unsigned short* Bh = (unsigned short*)(smem + 65536);    // 10 KB
    unsigned short* Bl = (unsigned short*)(smem + 75776);    // 10 KB
    float* as_ = (float*)smem;

    const int t    = threadIdx.x;
    const int lane = t & 63;
    const int wave = t >> 6;
    const int mb   = blockIdx.x * BM;

    f32x4 acc[2][5];
#pragma unroll
    for (int mt = 0; mt < 2; ++mt)
#pragma unroll
        for (int nt = 0; nt < 5; ++nt) acc[mt][nt] = (f32x4){0.f, 0.f, 0.f, 0.f};

    float4 vA[8];
    short8v vBh0, vBl0, vBh1, vBl1;

    // prefetch chunk 0
#pragma unroll
    for (int q = 0; q < 8; ++q) {
        int f = t + q * GT, row = f >> 4, col4 = f & 15;
        vA[q] = *reinterpret_cast<const float4*>(
            &x[(size_t)(mb + row) * KDIM + col4 * 4]);
    }
    vBh0 = *reinterpret_cast<const short8v*>(Whf + t * 8);
    vBl0 = *reinterpret_cast<const short8v*>(Wlf + t * 8);
    if (t < 128) {
        vBh1 = *reinterpret_cast<const short8v*>(Whf + (t + 512) * 8);
        vBl1 = *reinterpret_cast<const short8v*>(Wlf + (t + 512) * 8);
    }

#pragma unroll
    for (int c = 0; c < KDIM / BK; ++c) {
        // ---- write staged chunk c to LDS (convert A to bf16 hi/lo)
#pragma unroll
        for (int q = 0; q < 8; ++q) {
            int f = t + q * GT, row = f >> 4, col4 = f & 15;
            float vals[4] = {vA[q].x, vA[q].y, vA[q].z, vA[q].w};
            us4 h, lo;
#pragma unroll
            for (int j = 0; j < 4; ++j) {
                unsigned short hh = bf16_rne(vals[j]);
                float hf = __uint_as_float((unsigned)hh << 16);
                h[j]  = hh;
                lo[j] = bf16_rne(vals[j] - hf);
            }
            int sw   = (col4 >> 1) ^ (row & 7);
            int byte = row * (BK * 2) + sw * 16 + (col4 & 1) * 8;
            *reinterpret_cast<us4*>((char*)Ah + byte) = h;
            *reinterpret_cast<us4*>((char*)Al + byte) = lo;
        }
        *reinterpret_cast<short8v*>(Bh + t * 8) = vBh0;
        *reinterpret_cast<short8v*>(Bl + t * 8) = vBl0;
        if (t < 128) {
            *reinterpret_cast<short8v*>(Bh + (t + 512) * 8) = vBh1;
            *reinterpret_cast<short8v*>(Bl + (t + 512) * 8) = vBl1;
        }
        // ---- issue chunk c+1 loads (in flight across the compute phase)
        if (c + 1 < KDIM / BK) {
#pragma unroll
            for (int q = 0; q < 8; ++q) {
                int f = t + q * GT, row = f >> 4, col4 = f & 15;
                vA[q] = *reinterpret_cast<const float4*>(
                    &x[(size_t)(mb + row) * KDIM + (c + 1) * BK + col4 * 4]);
            }
            size_t base = (size_t)(c + 1) * 5120;
            vBh0 = *reinterpret_cast<const short8v*>(Whf + base + t * 8);
            vBl0 = *reinterpret_cast<const short8v*>(Wlf + base + t * 8);
            if (t < 128) {
                vBh1 = *reinterpret_cast<const short8v*>(Whf + base + (t + 512) * 8);
                vBl1 = *reinterpret_cast<const short8v*>(Wlf + base + (t + 512) * 8);
            }
        }
        __syncthreads();

        // ---- compute chunk c: 2 K-steps x 2 m-tiles x 5 n-tiles x 3 products
#pragma unroll
        for (int ks = 0; ks < BK / 32; ++ks) {
            short8v ah[2], al[2];
#pragma unroll
            for (int mt = 0; mt < 2; ++mt) {
                int row = wave * 32 + mt * 16 + (lane & 15);
                int c8  = ks * 4 + (lane >> 4);
                int sw  = c8 ^ (row & 7);
                int abyte = row * (BK * 2) + sw * 16;
                ah[mt] = *reinterpret_cast<const short8v*>((char*)Ah + abyte);
                al[mt] = *reinterpret_cast<const short8v*>((char*)Al + abyte);
            }
#pragma unroll
            for (int nt = 0; nt < 5; ++nt) {
                int boff = ((ks * 5 + nt) * 64 + lane) * 8;
                short8v bh = *reinterpret_cast<const short8v*>(Bh + boff);
                short8v bl = *reinterpret_cast<const short8v*>(Bl + boff);
#pragma unroll
                for (int mt = 0; mt < 2; ++mt) {
                    acc[mt][nt] = __builtin_amdgcn_mfma_f32_16x16x32_bf16(ah[mt], bh, acc[mt][nt], 0, 0, 0);
                    acc[mt][nt] = __builtin_amdgcn_mfma_f32_16x16x32_bf16(al[mt], bh, acc[mt][nt], 0, 0, 0);
                    acc[mt][nt] = __builtin_amdgcn_mfma_f32_16x16x32_bf16(ah[mt], bl, acc[mt][nt], 0, 0, 0);
                }
            }
        }
        __syncthreads();
    }

    // ---- epilogue: angles into LDS (A/B buffers dead after last barrier)
#pragma unroll
    for (int mt = 0; mt < 2; ++mt)
#pragma unroll
        for (int nt = 0; nt < 5; ++nt) {
            int n = nt * 16 + (lane & 15);
            if (n < NA) {
                float bias = b[n];
                int m = wave * 32 + mt * 16 + (lane >> 4) * 4;
                f32x4 v = acc[mt][nt];
#pragma unroll
                for (int j = 0; j < 4; ++j)
                    as_[n * ASTRIDE + m + j] = v[j] + bias;
            }
        }
    __syncthreads();

    // ---- circuit phase: 2 lanes/row (proven R5 structure), angles from LDS
    const int par = lane >> 5;
    const int rl  = (lane & 31) + wave * 32;    // local row 0..255

    float sr[32], si[32];
#pragma unroll
    for (int j = 0; j < 32; ++j) { sr[j] = 0.f; si[j] = 0.f; }
    if (par == 0) sr[0] = 1.f;

#define ANG(i) as_[(i) * ASTRIDE + rl]
#pragma unroll 1
    for (int lay = 0; lay < 3; ++lay) {
        const int base = lay * 23;
        rxx01_x(sr, si, ANG(base + 0));
        u30_x  (sr, si, par, ANG(base + 1), ANG(base + 2), ANG(base + 3));
        rxx_l<16, 8>(sr, si, ANG(base + 4));
        u3_l<16>(sr, si, ANG(base + 5),  ANG(base + 6),  ANG(base + 7));
        rxx_l<8, 4>(sr, si, ANG(base + 8));
        u3_l<8>(sr, si, ANG(base + 9),  ANG(base + 10), ANG(base + 11));
        rxx_l<4, 2>(sr, si, ANG(base + 12));
        u3_l<4>(sr, si, ANG(base + 13), ANG(base + 14), ANG(base + 15));
        rxx_l<2, 1>(sr, si, ANG(base + 16));
        u3_l<2>(sr, si, ANG(base + 17), ANG(base + 18), ANG(base + 19));
        u3_l<1>(sr, si, ANG(base + 20), ANG(base + 21), ANG(base + 22));
    }
#undef ANG

    float* o = out + (size_t)(mb + rl) * 128 + par * 32;
#pragma unroll
    for (int q = 0; q < 8; ++q)
        *reinterpret_cast<float4*>(&o[q * 4]) =
            make_float4(sr[q*4], sr[q*4+1], sr[q*4+2], sr[q*4+3]);
#pragma unroll
    for (int q = 0; q < 8; ++q)
        *reinterpret_cast<float4*>(&o[64 + q * 4]) =
            make_float4(si[q*4], si[q*4+1], si[q*4+2], si[q*4+3]);
}

// ==== fallback (ws too small): fp32 VALU GEMM + global-ang circuit ==========

__global__ __launch_bounds__(BLK, 1) void angles_gemm(
    const float* __restrict__ x, const float* __restrict__ W,
    const float* __restrict__ b, float* __restrict__ ang,
    int row_base, int pass_rows)
{
    const int t     = threadIdx.x;
    const int lrow0 = blockIdx.x * BLK;
    __shared__ float xs[BLK * LSTRIDE];
    float acc[NA];
#pragma unroll
    for (int a = 0; a < NA; ++a) acc[a] = b[a];
    for (int kc = 0; kc < KDIM; kc += 32) {
        __syncthreads();
#pragma unroll
        for (int it = 0; it < 8; ++it) {
            int f4 = it * BLK + t;
            int r  = f4 >> 3;
            int kq = f4 & 7;
            float4 v = *reinterpret_cast<const float4*>(
                &x[(size_t)(row_base + lrow0 + r) * KDIM + kc + kq * 4]);
            *reinterpret_cast<float4*>(&xs[r * LSTRIDE + kq * 4]) = v;
        }
        __syncthreads();
        float4 xv[8];
#pragma unroll
        for (int q = 0; q < 8; ++q)
            xv[q] = *reinterpret_cast<const float4*>(&xs[t * LSTRIDE + q * 4]);
#pragma unroll
        for (int a = 0; a < NA; ++a) {
            const float* wa = W + a * KDIM + kc;
            float s = 0.f;
#pragma unroll
            for (int q = 0; q < 8; ++q) {
                s += xv[q].x * wa[q * 4 + 0];
                s += xv[q].y * wa[q * 4 + 1];
                s += xv[q].z * wa[q * 4 + 2];
                s += xv[q].w * wa[q * 4 + 3];
            }
            acc[a] += s;
        }
    }
    const int lrow = lrow0 + t;
#pragma unroll
    for (int a = 0; a < NA; ++a)
        ang[(size_t)a * pass_rows + lrow] = acc[a];
}

__global__ __launch_bounds__(GT, 2) void circuit2g(
    const float* __restrict__ ang, float* __restrict__ out,
    int stride, int row_base)
{
    const int t    = threadIdx.x;
    const int lane = t & 63;
    const int wv   = t >> 6;
    const int par  = lane >> 5;
    const int rl   = (lane & 31) + wv * 32;
    const int row0 = blockIdx.x * CROWS;

    __shared__ float as_[NA][CROWS];
    for (int i = t; i < NA * CROWS; i += GT) {
        int a = i >> 8, r = i & 255;
        as_[a][r] = ang[(size_t)a * stride + row0 + r];
    }
    __syncthreads();

    float sr[32], si[32];
#pragma unroll
    for (int j = 0; j < 32; ++j) { sr[j] = 0.f; si[j] = 0.f; }
    if (par == 0) sr[0] = 1.f;

#define ANG(i) as_[(i)][rl]
#pragma unroll 1
    for (int lay = 0; lay < 3; ++lay) {
        const int base = lay * 23;
        rxx01_x(sr, si, ANG(base + 0));
        u30_x  (sr, si, par, ANG(base + 1), ANG(base + 2), ANG(base + 3));
        rxx_l<16, 8>(sr, si, ANG(base + 4));
        u3_l<16>(sr, si, ANG(base + 5),  ANG(base + 6),  ANG(base + 7));
        rxx_l<8, 4>(sr, si, ANG(base + 8));
        u3_l<8>(sr, si, ANG(base + 9),  ANG(base + 10), ANG(base + 11));
        rxx_l<4, 2>(sr, si, ANG(base + 12));
        u3_l<4>(sr, si, ANG(base + 13), ANG(base + 14), ANG(base + 15));
        rxx_l<2, 1>(sr, si, ANG(base + 16));
        u3_l<2>(sr, si, ANG(base + 17), ANG(base + 18), ANG(base + 19));
        u3_l<1>(sr, si, ANG(base + 20), ANG(base + 21), ANG(base + 22));
    }
#undef ANG

    float* o = out + (size_t)(row_base + row0 + rl) * 128 + par * 32;
#pragma unroll
    for (int q = 0; q < 8; ++q)
        *reinterpret_cast<float4*>(&o[q * 4]) =
            make_float4(sr[q*4], sr[q*4+1], sr[q*4+2], sr[q*4+3]);
#pragma unroll
    for (int q = 0; q < 8; ++q)
        *reinterpret_cast<float4*>(&o[64 + q * 4]) =
            make_float4(si[q*4], si[q*4+1], si[q*4+2], si[q*4+3]);
}

// ============================================================================

extern "C" void kernel_launch(void* const* d_in, const int* in_sizes, int n_in,
                              void* d_out, int out_size, void* d_ws, size_t ws_size,
                              hipStream_t stream) {
    const float* x = (const float*)d_in[0];
    const float* W = (const float*)d_in[1];
    const float* b = (const float*)d_in[2];
    float* out = (float*)d_out;
    const int batch = in_sizes[0] / KDIM;          // 65536

    const size_t wf_elems = (size_t)16 * 5 * 64 * 8;   // 40960 per buffer
    const size_t need     = 2 * wf_elems * 2;          // 160 KB

    if (ws_size >= need && (batch % BM) == 0) {
        unsigned short* Whf = (unsigned short*)d_ws;
        unsigned short* Wlf = Whf + wf_elems;
        hipLaunchKernelGGL(w_convert, dim3((16 * 5 * 64 + 255) / 256), dim3(256),
                           0, stream, W, Whf, Wlf);
        hipLaunchKernelGGL(qrnn_fused2, dim3(batch / BM), dim3(GT), 0, stream,
                           x, Whf, Wlf, b, out);
        return;
    }

    // fallback: fp32 VALU GEMM + circuit via global angles, multi-pass
    float* ws = (float*)d_ws;
    size_t max_rows = ws_size / ((size_t)NA * sizeof(float));
    int rows_per_pass = (int)((max_rows / CROWS) * CROWS);
    if (rows_per_pass > batch) rows_per_pass = batch;
    if (rows_per_pass < CROWS) return;   // cannot run
    for (int r0 = 0; r0 < batch; r0 += rows_per_pass) {
        int pr = batch - r0;
        if (pr > rows_per_pass) pr = rows_per_pass;
        hipLaunchKernelGGL(angles_gemm, dim3(pr / BLK), dim3(BLK), 0, stream,
                           x, W, b, ws, r0, pr);
        hipLaunchKernelGGL(circuit2g, dim3(pr / CROWS), dim3(GT), 0, stream,
                           ws, out, pr, r0);
    }
}

// Round 14
// 59.688 us; speedup vs baseline: 2.3198x; 1.0061x over previous
//
#include <hip/hip_runtime.h>

#define NA    69      // 3 * (4*6 - 1) angles
#define KDIM  512
#define BM    256     // fused: rows per block
#define BK    64      // gemm K chunk
#define GT    512     // fused block threads (8 waves)
#define CROWS 256
#define BLK   256
#define LSTRIDE 33
#define ASTRIDE 260   // angle LDS row stride (floats): 260%32=4 -> 2-way max

typedef __attribute__((ext_vector_type(8))) short short8v;   // 8 bf16 = 16B
typedef __attribute__((ext_vector_type(4))) float f32x4;
typedef __attribute__((ext_vector_type(4))) unsigned short us4;

__device__ __forceinline__ unsigned short bf16_rne(float x) {
    unsigned u = __float_as_uint(x);
    unsigned r = u + 0x7FFF + ((u >> 16) & 1);
    return (unsigned short)(r >> 16);
}

// ==== init: W (69x512 f32) -> bf16 hi/lo in MFMA-fragment order =============
// tid = ksg*320 + nt*64 + lane ; holds B[n=nt*16+(l&15)][k=ksg*32+(l>>4)*8+j]
__global__ void w_convert(const float* __restrict__ W,
                          unsigned short* __restrict__ Whf,
                          unsigned short* __restrict__ Wlf)
{
    int tid = blockIdx.x * 256 + threadIdx.x;
    if (tid >= 16 * 5 * 64) return;
    int ksg = tid / 320;
    int rem = tid % 320;
    int nt  = rem / 64;
    int l   = rem % 64;
    int n   = nt * 16 + (l & 15);
    int k   = ksg * 32 + (l >> 4) * 8;
#pragma unroll
    for (int j = 0; j < 8; ++j) {
        float w = (n < NA) ? W[(size_t)n * KDIM + k + j] : 0.f;
        unsigned short h = bf16_rne(w);
        float hf = __uint_as_float((unsigned)h << 16);
        Whf[(size_t)tid * 8 + j] = h;
        Wlf[(size_t)tid * 8 + j] = bf16_rne(w - hf);
    }
}

// ==== circuit gate helpers (2 lanes/row; par = lane>>5) =====================

template<int M0, int M1>
__device__ __forceinline__ void rxx_l(float* sr, float* si, float th) {
    float h = 0.5f * th, c, sn;
    __sincosf(h, &sn, &c);
    constexpr int M = M0 | M1;
#pragma unroll
    for (int j = 0; j < 32; ++j) {
        if (j & M0) continue;
        const int p = j ^ M;
        float ar = sr[j], ai = si[j], br = sr[p], bi = si[p];
        sr[j] = c * ar + sn * bi;
        si[j] = c * ai - sn * br;
        sr[p] = c * br + sn * ai;
        si[p] = c * bi - sn * ar;
    }
}

template<int M>
__device__ __forceinline__ void u3_l(float* sr, float* si,
                                     float th, float ph, float la) {
    float h = 0.5f * th;
    float ct, st, cph, sph, cla, sla;
    __sincosf(h,  &st,  &ct);
    __sincosf(ph, &sph, &cph);
    __sincosf(la, &sla, &cla);
    float cpl = cph * cla - sph * sla;
    float spl = sph * cla + cph * sla;
    float m01r = -cla * st, m01i = -sla * st;
    float m10r =  cph * st, m10i =  sph * st;
    float m11r =  cpl * ct, m11i =  spl * ct;
#pragma unroll
    for (int j = 0; j < 32; ++j) {
        if (j & M) continue;
        const int p = j | M;
        float ar = sr[j], ai = si[j], br = sr[p], bi = si[p];
        sr[j] = ct * ar + m01r * br - m01i * bi;
        si[j] = ct * ai + m01r * bi + m01i * br;
        sr[p] = m10r * ar - m10i * ai + m11r * br - m11i * bi;
        si[p] = m10r * ai + m10i * ar + m11r * bi + m11i * br;
    }
}

__device__ __forceinline__ void rxx01_x(float* sr, float* si, float th) {
    float h = 0.5f * th, c, sn;
    __sincosf(h, &sn, &c);
#pragma unroll
    for (int j = 0; j < 16; ++j) {
        const int p = j + 16;
        float crj = __shfl_xor(sr[p], 32), cij = __shfl_xor(si[p], 32);
        float crp = __shfl_xor(sr[j], 32), cip = __shfl_xor(si[j], 32);
        float aj = sr[j], bj = si[j], ap = sr[p], bp = si[p];
        sr[j] = c * aj + sn * cij;  si[j] = c * bj - sn * crj;
        sr[p] = c * ap + sn * cip;  si[p] = c * bp - sn * crp;
    }
}

__device__ __forceinline__ void u30_x(float* sr, float* si, int par,
                                      float th, float ph, float la) {
    float h = 0.5f * th;
    float ct, st, cph, sph, cla, sla;
    __sincosf(h,  &st,  &ct);
    __sincosf(ph, &sph, &cph);
    __sincosf(la, &sla, &cla);
    float cpl = cph * cla - sph * sla;
    float spl = sph * cla + cph * sla;
    float m01r = -cla * st, m01i = -sla * st;
    float m10r =  cph * st, m10i =  sph * st;
    float m11r =  cpl * ct, m11i =  spl * ct;
    float Ar = par ? m11r : ct,   Ai = par ? m11i : 0.f;
    float Br = par ? m10r : m01r, Bi = par ? m10i : m01i;
#pragma unroll
    for (int j = 0; j < 32; ++j) {
        float cr = __shfl_xor(sr[j], 32), ci = __shfl_xor(si[j], 32);
        float a = sr[j], bb = si[j];
        sr[j] = Ar * a  - Ai * bb + Br * cr - Bi * ci;
        si[j] = Ar * bb + Ai * a  + Br * ci + Bi * cr;
    }
}

// ==== fused: GEMM (MFMA, prefetched) -> LDS angles -> circuit ===============

__global__ __launch_bounds__(GT, 2) void qrnn_fused2(
    const float* __restrict__ x,
    const unsigned short* __restrict__ Whf, const unsigned short* __restrict__ Wlf,
    const float* __restrict__ b, float* __restrict__ out)
{
    // union LDS: GEMM phase uses Ah|Al|Bh|Bl (84 KB); circuit phase reuses it
    // as angle store as_[NA][ASTRIDE] (70.1 KB).
    __shared__ __align__(16) char smem[86016];
    unsigned short* Ah = (unsigned short*)smem;              // 32 KB
    unsigned short* Al = (unsigned short*)(smem + 32768);    // 32 KB
    unsigned short* Bh = (unsigned short*)(smem + 65536);    // 10 KB
    unsigned short* Bl = (unsigned short*)(smem + 75776);    // 10 KB
    float* as_ = (float*)smem;

    const int t    = threadIdx.x;
    const int lane = t & 63;
    const int wave = t >> 6;
    const int mb   = blockIdx.x * BM;

    f32x4 acc[2][5];
#pragma unroll
    for (int mt = 0; mt < 2; ++mt)
#pragma unroll
        for (int nt = 0; nt < 5; ++nt) acc[mt][nt] = (f32x4){0.f, 0.f, 0.f, 0.f};

    float4 vA[8];
    short8v vBh0, vBl0, vBh1, vBl1;

    // prefetch chunk 0
#pragma unroll
    for (int q = 0; q < 8; ++q) {
        int f = t + q * GT, row = f >> 4, col4 = f & 15;
        vA[q] = *reinterpret_cast<const float4*>(
            &x[(size_t)(mb + row) * KDIM + col4 * 4]);
    }
    vBh0 = *reinterpret_cast<const short8v*>(Whf + t * 8);
    vBl0 = *reinterpret_cast<const short8v*>(Wlf + t * 8);
    if (t < 128) {
        vBh1 = *reinterpret_cast<const short8v*>(Whf + (t + 512) * 8);
        vBl1 = *reinterpret_cast<const short8v*>(Wlf + (t + 512) * 8);
    }

#pragma unroll
    for (int c = 0; c < KDIM / BK; ++c) {
        // ---- write staged chunk c to LDS (convert A to bf16 hi/lo)
#pragma unroll
        for (int q = 0; q < 8; ++q) {
            int f = t + q * GT, row = f >> 4, col4 = f & 15;
            float vals[4] = {vA[q].x, vA[q].y, vA[q].z, vA[q].w};
            us4 h, lo;
#pragma unroll
            for (int j = 0; j < 4; ++j) {
                unsigned short hh = bf16_rne(vals[j]);
                float hf = __uint_as_float((unsigned)hh << 16);
                h[j]  = hh;
                lo[j] = bf16_rne(vals[j] - hf);
            }
            int sw   = (col4 >> 1) ^ (row & 7);
            int byte = row * (BK * 2) + sw * 16 + (col4 & 1) * 8;
            *reinterpret_cast<us4*>((char*)Ah + byte) = h;
            *reinterpret_cast<us4*>((char*)Al + byte) = lo;
        }
        *reinterpret_cast<short8v*>(Bh + t * 8) = vBh0;
        *reinterpret_cast<short8v*>(Bl + t * 8) = vBl0;
        if (t < 128) {
            *reinterpret_cast<short8v*>(Bh + (t + 512) * 8) = vBh1;
            *reinterpret_cast<short8v*>(Bl + (t + 512) * 8) = vBl1;
        }
        // ---- issue chunk c+1 loads (in flight across the compute phase)
        if (c + 1 < KDIM / BK) {
#pragma unroll
            for (int q = 0; q < 8; ++q) {
                int f = t + q * GT, row = f >> 4, col4 = f & 15;
                vA[q] = *reinterpret_cast<const float4*>(
                    &x[(size_t)(mb + row) * KDIM + (c + 1) * BK + col4 * 4]);
            }
            size_t base = (size_t)(c + 1) * 5120;
            vBh0 = *reinterpret_cast<const short8v*>(Whf + base + t * 8);
            vBl0 = *reinterpret_cast<const short8v*>(Wlf + base + t * 8);
            if (t < 128) {
                vBh1 = *reinterpret_cast<const short8v*>(Whf + base + (t + 512) * 8);
                vBl1 = *reinterpret_cast<const short8v*>(Wlf + base + (t + 512) * 8);
            }
        }
        __syncthreads();

        // ---- compute chunk c: 2 K-steps x 2 m-tiles x 5 n-tiles x 3 products
#pragma unroll
        for (int ks = 0; ks < BK / 32; ++ks) {
            short8v ah[2], al[2];
#pragma unroll
            for (int mt = 0; mt < 2; ++mt) {
                int row = wave * 32 + mt * 16 + (lane & 15);
                int c8  = ks * 4 + (lane >> 4);
                int sw  = c8 ^ (row & 7);
                int abyte = row * (BK * 2) + sw * 16;
                ah[mt] = *reinterpret_cast<const short8v*>((char*)Ah + abyte);
                al[mt] = *reinterpret_cast<const short8v*>((char*)Al + abyte);
            }
#pragma unroll
            for (int nt = 0; nt < 5; ++nt) {
                int boff = ((ks * 5 + nt) * 64 + lane) * 8;
                short8v bh = *reinterpret_cast<const short8v*>(Bh + boff);
                short8v bl = *reinterpret_cast<const short8v*>(Bl + boff);
#pragma unroll
                for (int mt = 0; mt < 2; ++mt) {
                    acc[mt][nt] = __builtin_amdgcn_mfma_f32_16x16x32_bf16(ah[mt], bh, acc[mt][nt], 0, 0, 0);
                    acc[mt][nt] = __builtin_amdgcn_mfma_f32_16x16x32_bf16(al[mt], bh, acc[mt][nt], 0, 0, 0);
                    acc[mt][nt] = __builtin_amdgcn_mfma_f32_16x16x32_bf16(ah[mt], bl, acc[mt][nt], 0, 0, 0);
                }
            }
        }
        __syncthreads();
    }

    // ---- epilogue: angles into LDS (A/B buffers dead after last barrier)
#pragma unroll
    for (int mt = 0; mt < 2; ++mt)
#pragma unroll
        for (int nt = 0; nt < 5; ++nt) {
            int n = nt * 16 + (lane & 15);
            if (n < NA) {
                float bias = b[n];
                int m = wave * 32 + mt * 16 + (lane >> 4) * 4;
                f32x4 v = acc[mt][nt];
#pragma unroll
                for (int j = 0; j < 4; ++j)
                    as_[n * ASTRIDE + m + j] = v[j] + bias;
            }
        }
    __syncthreads();

    // ---- circuit phase: 2 lanes/row (proven R5 structure), angles from LDS
    const int par = lane >> 5;
    const int rl  = (lane & 31) + wave * 32;    // local row 0..255

    float sr[32], si[32];
#pragma unroll
    for (int j = 0; j < 32; ++j) { sr[j] = 0.f; si[j] = 0.f; }
    if (par == 0) sr[0] = 1.f;

#define ANG(i) as_[(i) * ASTRIDE + rl]
#pragma unroll 1
    for (int lay = 0; lay < 3; ++lay) {
        const int base = lay * 23;
        rxx01_x(sr, si, ANG(base + 0));
        u30_x  (sr, si, par, ANG(base + 1), ANG(base + 2), ANG(base + 3));
        rxx_l<16, 8>(sr, si, ANG(base + 4));
        u3_l<16>(sr, si, ANG(base + 5),  ANG(base + 6),  ANG(base + 7));
        rxx_l<8, 4>(sr, si, ANG(base + 8));
        u3_l<8>(sr, si, ANG(base + 9),  ANG(base + 10), ANG(base + 11));
        rxx_l<4, 2>(sr, si, ANG(base + 12));
        u3_l<4>(sr, si, ANG(base + 13), ANG(base + 14), ANG(base + 15));
        rxx_l<2, 1>(sr, si, ANG(base + 16));
        u3_l<2>(sr, si, ANG(base + 17), ANG(base + 18), ANG(base + 19));
        u3_l<1>(sr, si, ANG(base + 20), ANG(base + 21), ANG(base + 22));
    }
#undef ANG

    float* o = out + (size_t)(mb + rl) * 128 + par * 32;
#pragma unroll
    for (int q = 0; q < 8; ++q)
        *reinterpret_cast<float4*>(&o[q * 4]) =
            make_float4(sr[q*4], sr[q*4+1], sr[q*4+2], sr[q*4+3]);
#pragma unroll
    for (int q = 0; q < 8; ++q)
        *reinterpret_cast<float4*>(&o[64 + q * 4]) =
            make_float4(si[q*4], si[q*4+1], si[q*4+2], si[q*4+3]);
}

// ==== fallback (ws too small): fp32 VALU GEMM + global-ang circuit ==========

__global__ __launch_bounds__(BLK, 1) void angles_gemm(
    const float* __restrict__ x, const float* __restrict__ W,
    const float* __restrict__ b, float* __restrict__ ang,
    int row_base, int pass_rows)
{
    const int t     = threadIdx.x;
    const int lrow0 = blockIdx.x * BLK;
    __shared__ float xs[BLK * LSTRIDE];
    float acc[NA];
#pragma unroll
    for (int a = 0; a < NA; ++a) acc[a] = b[a];
    for (int kc = 0; kc < KDIM; kc += 32) {
        __syncthreads();
#pragma unroll
        for (int it = 0; it < 8; ++it) {
            int f4 = it * BLK + t;
            int r  = f4 >> 3;
            int kq = f4 & 7;
            float4 v = *reinterpret_cast<const float4*>(
                &x[(size_t)(row_base + lrow0 + r) * KDIM + kc + kq * 4]);
            *reinterpret_cast<float4*>(&xs[r * LSTRIDE + kq * 4]) = v;
        }
        __syncthreads();
        float4 xv[8];
#pragma unroll
        for (int q = 0; q < 8; ++q)
            xv[q] = *reinterpret_cast<const float4*>(&xs[t * LSTRIDE + q * 4]);
#pragma unroll
        for (int a = 0; a < NA; ++a) {
            const float* wa = W + a * KDIM + kc;
            float s = 0.f;
#pragma unroll
            for (int q = 0; q < 8; ++q) {
                s += xv[q].x * wa[q * 4 + 0];
                s += xv[q].y * wa[q * 4 + 1];
                s += xv[q].z * wa[q * 4 + 2];
                s += xv[q].w * wa[q * 4 + 3];
            }
            acc[a] += s;
        }
    }
    const int lrow = lrow0 + t;
#pragma unroll
    for (int a = 0; a < NA; ++a)
        ang[(size_t)a * pass_rows + lrow] = acc[a];
}

__global__ __launch_bounds__(GT, 2) void circuit2g(
    const float* __restrict__ ang, float* __restrict__ out,
    int stride, int row_base)
{
    const int t    = threadIdx.x;
    const int lane = t & 63;
    const int wv   = t >> 6;
    const int par  = lane >> 5;
    const int rl   = (lane & 31) + wv * 32;
    const int row0 = blockIdx.x * CROWS;

    __shared__ float as_[NA][CROWS];
    for (int i = t; i < NA * CROWS; i += GT) {
        int a = i >> 8, r = i & 255;
        as_[a][r] = ang[(size_t)a * stride + row0 + r];
    }
    __syncthreads();

    float sr[32], si[32];
#pragma unroll
    for (int j = 0; j < 32; ++j) { sr[j] = 0.f; si[j] = 0.f; }
    if (par == 0) sr[0] = 1.f;

#define ANG(i) as_[(i)][rl]
#pragma unroll 1
    for (int lay = 0; lay < 3; ++lay) {
        const int base = lay * 23;
        rxx01_x(sr, si, ANG(base + 0));
        u30_x  (sr, si, par, ANG(base + 1), ANG(base + 2), ANG(base + 3));
        rxx_l<16, 8>(sr, si, ANG(base + 4));
        u3_l<16>(sr, si, ANG(base + 5),  ANG(base + 6),  ANG(base + 7));
        rxx_l<8, 4>(sr, si, ANG(base + 8));
        u3_l<8>(sr, si, ANG(base + 9),  ANG(base + 10), ANG(base + 11));
        rxx_l<4, 2>(sr, si, ANG(base + 12));
        u3_l<4>(sr, si, ANG(base + 13), ANG(base + 14), ANG(base + 15));
        rxx_l<2, 1>(sr, si, ANG(base + 16));
        u3_l<2>(sr, si, ANG(base + 17), ANG(base + 18), ANG(base + 19));
        u3_l<1>(sr, si, ANG(base + 20), ANG(base + 21), ANG(base + 22));
    }
#undef ANG

    float* o = out + (size_t)(row_base + row0 + rl) * 128 + par * 32;
#pragma unroll
    for (int q = 0; q < 8; ++q)
        *reinterpret_cast<float4*>(&o[q * 4]) =
            make_float4(sr[q*4], sr[q*4+1], sr[q*4+2], sr[q*4+3]);
#pragma unroll
    for (int q = 0; q < 8; ++q)
        *reinterpret_cast<float4*>(&o[64 + q * 4]) =
            make_float4(si[q*4], si[q*4+1], si[q*4+2], si[q*4+3]);
}

// ============================================================================

extern "C" void kernel_launch(void* const* d_in, const int* in_sizes, int n_in,
                              void* d_out, int out_size, void* d_ws, size_t ws_size,
                              hipStream_t stream) {
    const float* x = (const float*)d_in[0];
    const float* W = (const float*)d_in[1];
    const float* b = (const float*)d_in[2];
    float* out = (float*)d_out;
    const int batch = in_sizes[0] / KDIM;          // 65536

    const size_t wf_elems = (size_t)16 * 5 * 64 * 8;   // 40960 per buffer
    const size_t need     = 2 * wf_elems * 2;          // 160 KB

    if (ws_size >= need && (batch % BM) == 0) {
        unsigned short* Whf = (unsigned short*)d_ws;
        unsigned short* Wlf = Whf + wf_elems;
        hipLaunchKernelGGL(w_convert, dim3((16 * 5 * 64 + 255) / 256), dim3(256),
                           0, stream, W, Whf, Wlf);
        hipLaunchKernelGGL(qrnn_fused2, dim3(batch / BM), dim3(GT), 0, stream,
                           x, Whf, Wlf, b, out);
        return;
    }

    // fallback: fp32 VALU GEMM + circuit via global angles, multi-pass
    float* ws = (float*)d_ws;
    size_t max_rows = ws_size / ((size_t)NA * sizeof(float));
    int rows_per_pass = (int)((max_rows / CROWS) * CROWS);
    if (rows_per_pass > batch) rows_per_pass = batch;
    if (rows_per_pass < CROWS) return;   // cannot run
    for (int r0 = 0; r0 < batch; r0 += rows_per_pass) {
        int pr = batch - r0;
        if (pr > rows_per_pass) pr = rows_per_pass;
        hipLaunchKernelGGL(angles_gemm, dim3(pr / BLK), dim3(BLK), 0, stream,
                           x, W, b, ws, r0, pr);
        hipLaunchKernelGGL(circuit2g, dim3(pr / CROWS), dim3(GT), 0, stream,
                           ws, out, pr, r0);
    }
}